// Round 14
// baseline (39.783 us; speedup 1.0000x reference)
//
#include <hip/hip_runtime.h>
#include <hip/hip_bf16.h>

// Problem constants (match reference)
#define BB 2048   // batch
#define DD 512    // dim
#define RR 32     // relations

// Tiling: block = (relation r, e-chunk nc of NB, d-chunk kc of KB)
#define NB 64                // e-range per block
#define KB 128               // d-range per block
#define KS 32                // d per MFMA K-step
#define NKS (KB / KS)        // 4 K-steps, B-fragments held in registers
#define MT 96                // sample tile (+4 sigma: single-tile w.p. ~0.999)
#define SLCAP 256            // sample-list capacity
#define NPART 32             // nc(8) x kc(4) partial planes

#define A_STRIDE 132         // bf16 row stride for tail tile (~2-way max, free)

typedef __attribute__((ext_vector_type(8))) short bf16x8;
typedef __attribute__((ext_vector_type(4))) float f32x4;

__device__ __forceinline__ unsigned cvt_pk(float a, float b) {
    union { __hip_bfloat162 h2; unsigned u; } c;
    c.h2 = __float22bfloat162_rn(make_float2(a, b));   // v_cvt_pk_bf16_f32 (RNE)
    return c.u;
}

// rotation-reduce within each 16-lane DPP row (VALU pipe, no LDS)
template <int CTRL>
__device__ __forceinline__ float ror_add(float v) {
    int t = __builtin_amdgcn_update_dpp(0, __float_as_int(v), CTRL, 0xf, 0xf, true);
    return v + __int_as_float(t);
}
__device__ __forceinline__ float row16_sum(float v) {
    v = ror_add<0x128>(v);   // row_ror:8
    v = ror_add<0x124>(v);   // row_ror:4
    v = ror_add<0x122>(v);   // row_ror:2
    v = ror_add<0x121>(v);   // row_ror:1
    return v;
}

__launch_bounds__(256, 4)
__global__ void k_main(const float* __restrict__ head,
                       const float* __restrict__ tail,
                       const int* __restrict__ rel,
                       const float* __restrict__ W,
                       const float* __restrict__ b,
                       float* __restrict__ part,
                       int* __restrict__ cnt,
                       float* __restrict__ out) {
    // XCD-swizzled decode: all 32 blocks of a relation land on one XCD.
    const int bid = blockIdx.x;
    const int x = bid & 7, p = bid >> 3;
    const int r  = (x << 2) | (p >> 5);
    const int nc = (p >> 2) & 7;
    const int kc = p & 3;
    const int e0 = nc * NB;
    const int k0 = kc * KB;
    const int jplane = (nc << 2) | kc;
    const int tid = threadIdx.x;
    const int wave = tid >> 6;
    const int lane = tid & 63;
    const int l15 = lane & 15, lg = lane >> 4;

    __shared__ unsigned short A_lds[MT * A_STRIDE];        // 25.3 KiB
    __shared__ int slist[SLCAP];
    __shared__ float scpart[MT];
    __shared__ int cntS;
    __shared__ float bsS;
    __shared__ int lastS;

    if (tid == 0) cntS = 0;
    __syncthreads();           // nothing in flight yet: cheap drain

    // ---- issue rel + bias loads FIRST (small, L2-hot)
    const int4* rp = (const int4*)rel;
    int4 rv0 = rp[tid * 2 + 0];
    int4 rv1 = rp[tid * 2 + 1];
    float bv = (wave == 0) ? b[r * DD + e0 + lane] : 0.f;

    // ---- issue this thread's OWN W B-fragment: rows e=wave*16+l15,
    //      cols ks*32+lg*8 (+4). Every W element read by exactly one thread.
    const float* Wrow = W + ((size_t)r * DD + e0 + wave * 16 + l15) * DD + k0 + lg * 8;
    float4 wv[NKS][2];
    #pragma unroll
    for (int ks = 0; ks < NKS; ks++) {
        wv[ks][0] = *(const float4*)(Wrow + ks * KS);
        wv[ks][1] = *(const float4*)(Wrow + ks * KS + 4);
    }

    // ---- scan rel -> slist (LDS atomics); consumes only rv0/rv1
    {
        int base = tid * 8;
        if (rv0.x == r) { int q = atomicAdd(&cntS, 1); if (q < SLCAP) slist[q] = base; }
        if (rv0.y == r) { int q = atomicAdd(&cntS, 1); if (q < SLCAP) slist[q] = base + 1; }
        if (rv0.z == r) { int q = atomicAdd(&cntS, 1); if (q < SLCAP) slist[q] = base + 2; }
        if (rv0.w == r) { int q = atomicAdd(&cntS, 1); if (q < SLCAP) slist[q] = base + 3; }
        if (rv1.x == r) { int q = atomicAdd(&cntS, 1); if (q < SLCAP) slist[q] = base + 4; }
        if (rv1.y == r) { int q = atomicAdd(&cntS, 1); if (q < SLCAP) slist[q] = base + 5; }
        if (rv1.z == r) { int q = atomicAdd(&cntS, 1); if (q < SLCAP) slist[q] = base + 6; }
        if (rv1.w == r) { int q = atomicAdd(&cntS, 1); if (q < SLCAP) slist[q] = base + 7; }
    }
    // ---- bias partial for this e-range (folded in by kc==0 blocks only)
    {
        float v = bv;
        v = row16_sum(v);
        v += __shfl_xor(v, 16);
        v += __shfl_xor(v, 32);
        if (wave == 0 && lane == 0) bsS = v;
    }

    // RAW barrier (no vmcnt drain -> W loads stay in flight across it)
    asm volatile("s_waitcnt lgkmcnt(0)" ::: "memory");
    __builtin_amdgcn_s_barrier();
    __builtin_amdgcn_sched_barrier(0);

    const int n = min(cntS, SLCAP);
    const float biasv = (kc == 0) ? bsS : 0.f;
    const int ebase = e0 + wave * 16;

    bf16x8 bfr[NKS];
    bool converted = false;

    for (int ts = 0; ts < n; ts += MT) {
        const int tn = min(MT, n - ts);
        if (ts > 0) __syncthreads();           // protect scpart/A_lds reuse
        if (tid < MT) scpart[tid] = biasv;

        // ---- HOIST: head loads for this tile (drain at pre-MFMA barrier)
        float hreg[MT / 16][4];
        #pragma unroll
        for (int m = 0; m < MT / 16; m++) {
            #pragma unroll
            for (int q = 0; q < 4; q++) {
                int sl = m * 16 + lg * 4 + q;
                int si = min(sl, tn - 1);
                hreg[m][q] = head[(size_t)slist[ts + si] * DD + ebase + l15];
            }
        }

        // ---- stage tail[tn x KB] fp32 -> bf16 A_lds; pad rows zeroed
        #pragma unroll
        for (int i = 0; i < (MT * KB / 4) / 256; i++) {    // 12 iters
            int idx = i * 256 + tid;
            int row = idx >> 5, fc = idx & 31;
            float4 v = make_float4(0.f, 0.f, 0.f, 0.f);
            if (row < tn)
                v = *(const float4*)(tail + (size_t)slist[ts + row] * DD + k0 + fc * 4);
            unsigned* pa = (unsigned*)&A_lds[row * A_STRIDE + fc * 4];
            pa[0] = cvt_pk(v.x, v.y);
            pa[1] = cvt_pk(v.z, v.w);
        }
        __syncthreads();   // staging + hreg + W regs all drained here

        // ---- convert W fragment to bf16 once
        if (!converted) {
            #pragma unroll
            for (int ks = 0; ks < NKS; ks++) {
                union { unsigned u[4]; bf16x8 v; } bb;
                bb.u[0] = cvt_pk(wv[ks][0].x, wv[ks][0].y);
                bb.u[1] = cvt_pk(wv[ks][0].z, wv[ks][0].w);
                bb.u[2] = cvt_pk(wv[ks][1].x, wv[ks][1].y);
                bb.u[3] = cvt_pk(wv[ks][1].z, wv[ks][1].w);
                bfr[ks] = bb.v;
            }
            converted = true;
        }

        f32x4 acc[MT / 16];
        #pragma unroll
        for (int m = 0; m < MT / 16; m++) acc[m] = (f32x4){0.f, 0.f, 0.f, 0.f};

        #pragma unroll
        for (int ks = 0; ks < NKS; ks++) {
            #pragma unroll
            for (int m = 0; m < MT / 16; m++) {
                bf16x8 af = *(const bf16x8*)&A_lds[(m * 16 + l15) * A_STRIDE + ks * KS + lg * 8];
                acc[m] = __builtin_amdgcn_mfma_f32_16x16x32_bf16(af, bfr[ks], acc[m], 0, 0, 0);
            }
        }

        // ---- epilogue (register-only): scpart[s] += sum_e acc[s,e]*head[s,e]
        // C layout: col(e) = l15, row(s) = 4*lg + q  (m89-verified)
        #pragma unroll
        for (int m = 0; m < MT / 16; m++) {
            #pragma unroll
            for (int q = 0; q < 4; q++) {
                int sl = m * 16 + lg * 4 + q;
                float v = acc[m][q] * hreg[m][q];          // pad rows: acc==0
                v = row16_sum(v);                          // reduce over e (DPP)
                if (l15 == 0 && sl < tn) atomicAdd(&scpart[sl], v);
            }
        }
        __syncthreads();
        // ---- plane store at the COHERENCE POINT (uncontended atomicExch:
        //      device-scope atomics bypass the non-coherent per-XCD L2s, so
        //      no threadfence/wbl2 is ever needed -- avoids R5's disaster)
        if (tid < tn)
            atomicExch(&part[(size_t)slist[ts + tid] * NPART + jplane], scpart[tid]);
    }

    // ---- last-arriving block of this relation reduces the 32 planes.
    // __syncthreads drains vmcnt (exch acked at coherence point) BEFORE the
    // flag RMW, so old==31 implies all 32 planes globally visible.
    __syncthreads();
    if (tid == 0) lastS = (atomicAdd(&cnt[r], 1) == NPART - 1);
    __syncthreads();
    if (lastS) {
        for (int s = tid; s < n; s += 256) {
            float* ps = part + (size_t)slist[s] * NPART;
            float acc = 0.f;
            #pragma unroll
            for (int j = 0; j < NPART; j++)
                acc += atomicAdd(&ps[j], 0.f);   // coherence-point read, fixed order
            out[slist[s]] = acc;                 // deterministic
        }
    }
}

extern "C" void kernel_launch(void* const* d_in, const int* in_sizes, int n_in,
                              void* d_out, int out_size, void* d_ws, size_t ws_size,
                              hipStream_t stream) {
    const float* head = (const float*)d_in[0];
    const float* tail = (const float*)d_in[1];
    const int*   rel  = (const int*)d_in[2];
    const float* W    = (const float*)d_in[3];
    const float* b    = (const float*)d_in[4];
    float* out  = (float*)d_out;
    float* part = (float*)d_ws;                               // BB x NPART floats
    int*   cnt  = (int*)((char*)d_ws + (size_t)BB * NPART * sizeof(float));

    hipMemsetAsync(cnt, 0, RR * sizeof(int), stream);         // graph-safe
    k_main<<<RR * (DD / NB) * (DD / KB), 256, 0, stream>>>(head, tail, rel, W, b,
                                                           part, cnt, out);
}

// Round 15
// 21.241 us; speedup vs baseline: 1.8729x; 1.8729x over previous
//
#include <hip/hip_runtime.h>
#include <hip/hip_bf16.h>

// Problem constants (match reference)
#define BB 2048   // batch
#define DD 512    // dim
#define RR 32     // relations

// Tiling: block = (relation r, e-chunk nc of NB, d-chunk kc of KB)
#define NB 64                // e-range per block
#define KB 128               // d-range per block
#define KS 32                // d per MFMA K-step
#define NKS (KB / KS)        // 4 K-steps, B-fragments held in registers
#define MT 96                // sample tile (+4 sigma: single-tile w.p. ~0.999)
#define SLCAP 256            // sample-list capacity
#define NPART 32             // nc(8) x kc(4) partial planes

#define A_STRIDE 132         // bf16 row stride for tail tile (~2-way max, free)

typedef __attribute__((ext_vector_type(8))) short bf16x8;
typedef __attribute__((ext_vector_type(4))) float f32x4;

__device__ __forceinline__ unsigned cvt_pk(float a, float b) {
    union { __hip_bfloat162 h2; unsigned u; } c;
    c.h2 = __float22bfloat162_rn(make_float2(a, b));   // v_cvt_pk_bf16_f32 (RNE)
    return c.u;
}

// rotation-reduce within each 16-lane DPP row (VALU pipe, no LDS)
template <int CTRL>
__device__ __forceinline__ float ror_add(float v) {
    int t = __builtin_amdgcn_update_dpp(0, __float_as_int(v), CTRL, 0xf, 0xf, true);
    return v + __int_as_float(t);
}
__device__ __forceinline__ float row16_sum(float v) {
    v = ror_add<0x128>(v);   // row_ror:8
    v = ror_add<0x124>(v);   // row_ror:4
    v = ror_add<0x122>(v);   // row_ror:2
    v = ror_add<0x121>(v);   // row_ror:1
    return v;
}

__launch_bounds__(256, 4)
__global__ void k_main(const float* __restrict__ head,
                       const float* __restrict__ tail,
                       const int* __restrict__ rel,
                       const float* __restrict__ W,
                       const float* __restrict__ b,
                       float* __restrict__ part) {
    // XCD-swizzled decode: all 32 blocks of a relation land on one XCD.
    const int bid = blockIdx.x;
    const int x = bid & 7, p = bid >> 3;
    const int r  = (x << 2) | (p >> 5);
    const int nc = (p >> 2) & 7;
    const int kc = p & 3;
    const int e0 = nc * NB;
    const int k0 = kc * KB;
    const int jplane = (nc << 2) | kc;
    const int tid = threadIdx.x;
    const int wave = tid >> 6;
    const int lane = tid & 63;
    const int l15 = lane & 15, lg = lane >> 4;

    __shared__ unsigned short A_lds[MT * A_STRIDE];        // 25.3 KiB
    __shared__ int slist[SLCAP];
    __shared__ float scpart[MT];
    __shared__ int cntS;
    __shared__ float bsS;

    if (tid == 0) cntS = 0;
    __syncthreads();           // nothing in flight yet: cheap drain

    // ---- issue rel + bias loads FIRST (small; consuming them waits only on
    //      themselves, not the W burst issued after)
    const int4* rp = (const int4*)rel;
    int4 rv0 = rp[tid * 2 + 0];
    int4 rv1 = rp[tid * 2 + 1];
    float bv = (wave == 0) ? b[r * DD + e0 + lane] : 0.f;

    // ---- issue this thread's OWN W B-fragment: rows e=wave*16+l15,
    //      cols ks*32+lg*8 (+4). Every W element read by exactly one thread.
    const float* Wrow = W + ((size_t)r * DD + e0 + wave * 16 + l15) * DD + k0 + lg * 8;
    float4 wv[NKS][2];
    #pragma unroll
    for (int ks = 0; ks < NKS; ks++) {
        wv[ks][0] = *(const float4*)(Wrow + ks * KS);
        wv[ks][1] = *(const float4*)(Wrow + ks * KS + 4);
    }

    // ---- ballot-compaction scan: 1 LDS atomic per wave per slot (vs 1 per
    //      match) -- removes same-address RMW serialization at the chain head
    {
        const int base = tid * 8;
        const int vals[8] = {rv0.x, rv0.y, rv0.z, rv0.w, rv1.x, rv1.y, rv1.z, rv1.w};
        #pragma unroll
        for (int j = 0; j < 8; j++) {
            bool m = (vals[j] == r);
            unsigned long long bal = __ballot(m);
            if (bal) {
                int lead = __ffsll((unsigned long long)bal) - 1;
                int wbase = 0;
                if (lane == lead) wbase = atomicAdd(&cntS, __popcll(bal));
                wbase = __shfl(wbase, lead);
                if (m) {
                    int pos = wbase + __popcll(bal & ((1ULL << lane) - 1));
                    if (pos < SLCAP) slist[pos] = base + j;
                }
            }
        }
    }
    // ---- bias partial for this e-range (folded in by kc==0 blocks only)
    {
        float v = bv;
        v = row16_sum(v);
        v += __shfl_xor(v, 16);
        v += __shfl_xor(v, 32);
        if (wave == 0 && lane == 0) bsS = v;
    }

    // RAW barrier (no vmcnt drain -> W loads stay in flight across it)
    asm volatile("s_waitcnt lgkmcnt(0)" ::: "memory");
    __builtin_amdgcn_s_barrier();
    __builtin_amdgcn_sched_barrier(0);

    const int n = min(cntS, SLCAP);
    const float biasv = (kc == 0) ? bsS : 0.f;
    const int ebase = e0 + wave * 16;

    bf16x8 bfr[NKS];

    for (int ts = 0; ts < n; ts += MT) {
        const int tn = min(MT, n - ts);
        if (ts > 0) __syncthreads();           // protect scpart/A_lds reuse
        if (tid < MT) scpart[tid] = biasv;

        // ---- HOIST: head loads for this tile (drain at pre-MFMA barrier,
        //      so the post-MFMA epilogue has zero global latency on it)
        float hreg[MT / 16][4];
        #pragma unroll
        for (int m = 0; m < MT / 16; m++) {
            #pragma unroll
            for (int q = 0; q < 4; q++) {
                int sl = m * 16 + lg * 4 + q;
                int si = min(sl, tn - 1);
                hreg[m][q] = head[(size_t)slist[ts + si] * DD + ebase + l15];
            }
        }

        // ---- stage tail[tn x KB] fp32 -> bf16 A_lds; pad rows zeroed
        #pragma unroll
        for (int i = 0; i < (MT * KB / 4) / 256; i++) {    // 12 iters
            int idx = i * 256 + tid;
            int row = idx >> 5, fc = idx & 31;
            float4 v = make_float4(0.f, 0.f, 0.f, 0.f);
            if (row < tn)
                v = *(const float4*)(tail + (size_t)slist[ts + row] * DD + k0 + fc * 4);
            unsigned* pa = (unsigned*)&A_lds[row * A_STRIDE + fc * 4];
            pa[0] = cvt_pk(v.x, v.y);
            pa[1] = cvt_pk(v.z, v.w);
        }

        // ---- convert W fragment to bf16 IN THE STAGE SHADOW (W arrived long
        //      ago; only the younger head loads are still outstanding, so this
        //      waits ~nothing and runs before the barrier instead of after)
        if (ts == 0) {
            #pragma unroll
            for (int ks = 0; ks < NKS; ks++) {
                union { unsigned u[4]; bf16x8 v; } bb;
                bb.u[0] = cvt_pk(wv[ks][0].x, wv[ks][0].y);
                bb.u[1] = cvt_pk(wv[ks][0].z, wv[ks][0].w);
                bb.u[2] = cvt_pk(wv[ks][1].x, wv[ks][1].y);
                bb.u[3] = cvt_pk(wv[ks][1].z, wv[ks][1].w);
                bfr[ks] = bb.v;
            }
        }
        __syncthreads();   // staging + hreg all drained here

        f32x4 acc[MT / 16];
        #pragma unroll
        for (int m = 0; m < MT / 16; m++) acc[m] = (f32x4){0.f, 0.f, 0.f, 0.f};

        #pragma unroll
        for (int ks = 0; ks < NKS; ks++) {
            #pragma unroll
            for (int m = 0; m < MT / 16; m++) {
                bf16x8 af = *(const bf16x8*)&A_lds[(m * 16 + l15) * A_STRIDE + ks * KS + lg * 8];
                acc[m] = __builtin_amdgcn_mfma_f32_16x16x32_bf16(af, bfr[ks], acc[m], 0, 0, 0);
            }
        }

        // ---- epilogue (register-only): scpart[s] += sum_e acc[s,e]*head[s,e]
        // C layout: col(e) = l15, row(s) = 4*lg + q  (m89-verified)
        #pragma unroll
        for (int m = 0; m < MT / 16; m++) {
            #pragma unroll
            for (int q = 0; q < 4; q++) {
                int sl = m * 16 + lg * 4 + q;
                float v = acc[m][q] * hreg[m][q];          // pad rows: acc==0
                v = row16_sum(v);                          // reduce over e (DPP)
                if (l15 == 0 && sl < tn) atomicAdd(&scpart[sl], v);
            }
        }
        __syncthreads();
        // plane (nc,kc) of each sample written by exactly this block: plain
        // store, sample-major so k_reduce reads contiguous 128B per sample
        if (tid < tn) part[(size_t)slist[ts + tid] * NPART + jplane] = scpart[tid];
    }
}

__global__ void k_reduce(const float* __restrict__ part, float* __restrict__ out) {
    int i = blockIdx.x * 256 + threadIdx.x;
    const float4* p = (const float4*)(part + (size_t)i * NPART);
    float s = 0.f;
    #pragma unroll
    for (int j = 0; j < NPART / 4; j++) {
        float4 v = p[j];
        s += v.x + v.y + v.z + v.w;
    }
    out[i] = s;   // fixed order -> deterministic
}

extern "C" void kernel_launch(void* const* d_in, const int* in_sizes, int n_in,
                              void* d_out, int out_size, void* d_ws, size_t ws_size,
                              hipStream_t stream) {
    const float* head = (const float*)d_in[0];
    const float* tail = (const float*)d_in[1];
    const int*   rel  = (const int*)d_in[2];
    const float* W    = (const float*)d_in[3];
    const float* b    = (const float*)d_in[4];
    float* out  = (float*)d_out;
    float* part = (float*)d_ws;   // BB x NPART floats = 256 KiB

    k_main<<<RR * (DD / NB) * (DD / KB), 256, 0, stream>>>(head, tail, rel, W, b, part);
    k_reduce<<<BB / 256, 256, 0, stream>>>(part, out);
}